// Round 18
// baseline (76.664 us; speedup 1.0000x reference)
//
#include <hip/hip_runtime.h>

#define D_FEAT   64
#define BSHIFT   7                // 128 nodes per coarse bucket
#define BROWS    (1 << BSHIFT)
#define SRC_MASK 0x1FFFFFF        // 25 bits for src index
#define CAPF     2816             // bucket region stride in rec[]
#define CAPF_RAW 1920             // raw-record cap (mean 1600, sd 40 -> 8 sigma)
#define OVF_CAP  16384
#define CAP_R5   2560             // mid-tier sort capacity
#define B_SC     1024             // chunking blocks for count/write phases

__device__ __forceinline__ unsigned short f2bf(float f) {
    unsigned u = __float_as_uint(f);
    u += 0x7FFF + ((u >> 16) & 1);   // round-to-nearest-even
    return (unsigned short)(u >> 16);
}
__device__ __forceinline__ float lo16f(unsigned u) { return __uint_as_float(u << 16); }
__device__ __forceinline__ float hi16f(unsigned u) { return __uint_as_float(u & 0xFFFF0000u); }
__device__ __forceinline__ float bf2f(unsigned short h) { return __uint_as_float(((unsigned)h) << 16); }

// ---------------- fallback (round-1) atomic kernel ----------------
__global__ void lgconv_scatter_atomic(const float* __restrict__ src_x,
                                      const int* __restrict__ src_idx,
                                      const int* __restrict__ dst_idx,
                                      const float* __restrict__ ew,
                                      float* __restrict__ out,
                                      int n_edges) {
    int tid = blockIdx.x * blockDim.x + threadIdx.x;
    int edge = tid >> 4;
    int l    = tid & 15;
    if (edge >= n_edges) return;
    int s = src_idx[edge];
    int d = dst_idx[edge];
    float w = ew[edge];
    const float4 v = *reinterpret_cast<const float4*>(src_x + (size_t)s * D_FEAT + l * 4);
    float* o = out + (size_t)d * D_FEAT + l * 4;
    atomicAdd(o + 0, w * v.x);
    atomicAdd(o + 1, w * v.y);
    atomicAdd(o + 2, w * v.z);
    atomicAdd(o + 3, w * v.w);
}

// ======== FULL PATH: deterministic scatter + fused in-LDS sort+gather ========

// Fused: src_x -> bf16 rows + per-(block,bucket) count matrix C[bucket*B_SC+blk].
// Edge hist pass vectorized: int4 dst loads (4 edges/thread).
__global__ void k_conv_hist(const float* __restrict__ src_x, unsigned short* __restrict__ sxb,
                            const int* __restrict__ dst, int* __restrict__ C,
                            int NE4, int E, int NB) {
    extern __shared__ int h[];
    int t = threadIdx.x, blk = blockIdx.x;
    int gsz = gridDim.x * blockDim.x;
    for (int i = blk * blockDim.x + t; i < NE4; i += gsz) {
        float4 v = reinterpret_cast<const float4*>(src_x)[i];
        ushort4 o;
        o.x = f2bf(v.x); o.y = f2bf(v.y); o.z = f2bf(v.z); o.w = f2bf(v.w);
        reinterpret_cast<ushort4*>(sxb)[i] = o;
    }
    for (int i = t; i < NB; i += blockDim.x) h[i] = 0;
    __syncthreads();
    int chunk = (((E + gridDim.x - 1) / gridDim.x) + 3) & ~3;   // multiple of 4
    int e0 = blk * chunk, e1 = min(E, e0 + chunk);
    if (e0 < e1) {
        int nv = (e1 - e0) >> 2;
        for (int g = t; g < nv; g += blockDim.x) {
            int4 d4 = *reinterpret_cast<const int4*>(dst + e0 + g * 4);
            atomicAdd(&h[d4.x >> BSHIFT], 1);
            atomicAdd(&h[d4.y >> BSHIFT], 1);
            atomicAdd(&h[d4.z >> BSHIFT], 1);
            atomicAdd(&h[d4.w >> BSHIFT], 1);
        }
        for (int e = e0 + nv * 4 + t; e < e1; e += blockDim.x)
            atomicAdd(&h[dst[e] >> BSHIFT], 1);
    }
    __syncthreads();
    for (int i = t; i < NB; i += blockDim.x)
        C[i * B_SC + blk] = h[i];
}

// Per-bucket exclusive scan over the B_SC block counts, in place.
__global__ __launch_bounds__(B_SC)
void k_scan_det(int* __restrict__ C, int* __restrict__ btot,
                int* __restrict__ ovf_cnt, int NB) {
    __shared__ int tmp[B_SC];
    int b = blockIdx.x, t = threadIdx.x;
    int v = C[b * B_SC + t];
    tmp[t] = v;
    __syncthreads();
    for (int d = 1; d < B_SC; d <<= 1) {
        int x = (t >= d) ? tmp[t - d] : 0;
        __syncthreads();
        tmp[t] += x;
        __syncthreads();
    }
    C[b * B_SC + t] = b * CAPF + tmp[t] - v;
    if (t == B_SC - 1) btot[b] = tmp[t];
    if (b == 0 && t == 0) *ovf_cnt = 0;
}

// Write records at exact precomputed positions. ZERO global atomics.
// Vectorized: 4 edges/thread via int4/float4 loads (MLP~3 on the input loads).
__global__ void k_scatter_det(const int* __restrict__ src, const int* __restrict__ dst,
                              const float* __restrict__ ew, const int* __restrict__ OFF,
                              int2* __restrict__ rec, int* __restrict__ ovf,
                              int* __restrict__ ovf_cnt, int E, int NB) {
    extern __shared__ int h[];
    int t = threadIdx.x, blk = blockIdx.x;
    for (int i = t; i < NB; i += blockDim.x) h[i] = OFF[i * B_SC + blk];
    __syncthreads();
    int chunk = (((E + gridDim.x - 1) / gridDim.x) + 3) & ~3;   // multiple of 4
    int e0 = blk * chunk, e1 = min(E, e0 + chunk);
    if (e0 >= e1) return;

    int nv = (e1 - e0) >> 2;
    for (int g = t; g < nv; g += blockDim.x) {
        int    base4 = e0 + g * 4;
        int4   d4 = *reinterpret_cast<const int4*>(dst + base4);
        int4   s4 = *reinterpret_cast<const int4*>(src + base4);
        float4 w4 = *reinterpret_cast<const float4*>(ew + base4);
        #pragma unroll
        for (int q = 0; q < 4; ++q) {
            int   d = (q == 0) ? d4.x : (q == 1) ? d4.y : (q == 2) ? d4.z : d4.w;
            int   s = (q == 0) ? s4.x : (q == 1) ? s4.y : (q == 2) ? s4.z : s4.w;
            float w = (q == 0) ? w4.x : (q == 1) ? w4.y : (q == 2) ? w4.z : w4.w;
            int b = d >> BSHIFT;
            int pos = atomicAdd(&h[b], 1);           // LDS only
            if (pos < b * CAPF + CAPF_RAW)
                rec[pos] = make_int2(s | ((d & (BROWS - 1)) << 25),
                                     ((int)f2bf(w)) << 16);
            else {
                int o = atomicAdd(ovf_cnt, 1);       // statistically never
                if (o < OVF_CAP) ovf[o] = base4 + q;
            }
        }
    }
    for (int e = e0 + nv * 4 + t; e < e1; e += blockDim.x) {
        int d = dst[e];
        int b = d >> BSHIFT;
        int pos = atomicAdd(&h[b], 1);
        if (pos < b * CAPF + CAPF_RAW)
            rec[pos] = make_int2(src[e] | ((d & (BROWS - 1)) << 25),
                                 ((int)f2bf(ew[e])) << 16);
        else {
            int o = atomicAdd(ovf_cnt, 1);
            if (o < OVF_CAP) ovf[o] = e;
        }
    }
}

// One block (8 waves) per bucket. Records stream ONCE from global into an
// arrival-order LDS buffer L (hist computed on the fly), then LDS->LDS permute
// into sorted S. Gather: ONE NODE PER 8-LANE GROUP, branch-free inner loop,
// 8 independent row loads in flight (MLP=8), no cross-group reduce.
__global__ __launch_bounds__(512)
void k_sort_gather(const int* __restrict__ btot, const int2* __restrict__ rec,
                   const unsigned short* __restrict__ sxb,
                   const int* __restrict__ src, const int* __restrict__ dst,
                   const float* __restrict__ ew,
                   const int* __restrict__ ovf, const int* __restrict__ ovf_cnt,
                   float* __restrict__ out, int N) {
    __shared__ int2 L[CAPF_RAW];      // 15 KB arrival-order records
    __shared__ int2 S[CAPF_RAW];      // 15 KB node-sorted records
    __shared__ int hist[BROWS];
    __shared__ int incl[BROWS];
    __shared__ int offl[BROWS];
    int b = blockIdx.x, t = threadIdx.x;
    int gbase = b * CAPF;
    int count = btot[b]; if (count > CAPF_RAW) count = CAPF_RAW;
    int nbase = b << BSHIFT;

    // ---- single global read: fill L + hist ----
    for (int i = t; i < BROWS; i += blockDim.x) hist[i] = 0;
    __syncthreads();
    for (int i = t; i < count; i += blockDim.x) {
        int2 r = rec[gbase + i];
        L[i] = r;
        atomicAdd(&hist[(r.x >> 25) & (BROWS - 1)], 1);
    }
    __syncthreads();
    if (t < BROWS) incl[t] = hist[t];
    __syncthreads();
    for (int d = 1; d < BROWS; d <<= 1) {
        int v = (t < BROWS && t >= d) ? incl[t - d] : 0;
        __syncthreads();
        if (t < BROWS) incl[t] += v;
        __syncthreads();
    }
    if (t < BROWS) {
        int ex = incl[t] - hist[t];
        offl[t] = ex;
        incl[t] = ex;                    // write cursor
    }
    __syncthreads();
    for (int i = t; i < count; i += blockDim.x) {
        int2 r = L[i];                   // LDS -> LDS permute
        int pos = atomicAdd(&incl[(r.x >> 25) & (BROWS - 1)], 1);
        S[pos] = r;
    }
    __syncthreads();

    // ---- gather: 8 nodes per wave, one per 8-lane group ----
    int wave = t >> 6, lane = t & 63;
    int grp = lane >> 3;      // node within the batch of 8
    int sub = lane & 7;       // dwordx4 slot within the 128 B bf16 row

    for (int kb = wave * 16; kb < wave * 16 + 16; kb += 8) {
        int k    = kb + grp;            // this group's local node
        int off  = offl[k];
        int deg  = hist[k];             // group-uniform per lane
        float a0 = 0.f, a1 = 0.f, a2 = 0.f, a3 = 0.f,
              a4 = 0.f, a5 = 0.f, a6 = 0.f, a7 = 0.f;

        for (int c = 0; __any(c < deg); c += 8) {
            int rs = 0; float rw = 0.f;
            if (c + sub < deg) {                     // in-bounds: off+c+sub < count
                int2 r = S[off + c + sub];
                rs = r.x;
                rw = hi16f((unsigned)r.y);
            }
            #pragma unroll
            for (int i = 0; i < 8; ++i) {
                int jl = (grp << 3) + i;             // intra-group broadcast
                int   s = __shfl(rs, jl) & SRC_MASK; // pad slots -> row 0 (L1-hot)
                float w = __shfl(rw, jl);            // pad slots -> w = 0
                const uint4 u = *reinterpret_cast<const uint4*>(
                    sxb + (size_t)s * D_FEAT + sub * 8);
                a0 = fmaf(w, lo16f(u.x), a0); a1 = fmaf(w, hi16f(u.x), a1);
                a2 = fmaf(w, lo16f(u.y), a2); a3 = fmaf(w, hi16f(u.y), a3);
                a4 = fmaf(w, lo16f(u.z), a4); a5 = fmaf(w, hi16f(u.z), a5);
                a6 = fmaf(w, lo16f(u.w), a6); a7 = fmaf(w, hi16f(u.w), a7);
            }
        }
        int node = nbase + k;
        if (node < N) {
            float* o = out + (size_t)node * D_FEAT + sub * 8;
            *reinterpret_cast<float4*>(o)     = make_float4(a0, a1, a2, a3);
            *reinterpret_cast<float4*>(o + 4) = make_float4(a4, a5, a6, a7);
        }
    }

    // ---- overflow replay for this bucket (normally n == 0) ----
    __syncthreads();
    int n = *ovf_cnt; if (n > OVF_CAP) n = OVF_CAP;
    for (int idx = t; idx < n; idx += blockDim.x) {
        int e = ovf[idx];
        int d = dst[e];
        if ((d >> BSHIFT) != b) continue;
        float w = ew[e];
        int s = src[e];
        for (int q = 0; q < D_FEAT; ++q)
            atomicAdd(out + (size_t)d * D_FEAT + q,
                      w * bf2f(sxb[(size_t)s * D_FEAT + q]));
    }
}

// ================= MID TIER (proven round-5 pipeline, f32) =================

__global__ void k_hist_b(const int* __restrict__ dst, int* __restrict__ counts_b,
                         int E, int NB) {
    extern __shared__ int h[];
    for (int i = threadIdx.x; i < NB; i += blockDim.x) h[i] = 0;
    __syncthreads();
    int chunk = (E + gridDim.x - 1) / gridDim.x;
    int e0 = blockIdx.x * chunk;
    int e1 = min(E, e0 + chunk);
    for (int e = e0 + threadIdx.x; e < e1; e += blockDim.x)
        atomicAdd(&h[dst[e] >> BSHIFT], 1);
    __syncthreads();
    for (int i = threadIdx.x; i < NB; i += blockDim.x)
        if (h[i]) atomicAdd(&counts_b[i], h[i]);
}

__global__ void k_scan_b(const int* __restrict__ counts, int* __restrict__ offsets,
                         int* __restrict__ cursor, int NB) {
    __shared__ int tmp[1024];
    __shared__ int carry;
    int t = threadIdx.x;
    if (t == 0) carry = 0;
    __syncthreads();
    for (int base = 0; base < NB; base += 1024) {
        int i = base + t;
        int v = (i < NB) ? counts[i] : 0;
        tmp[t] = v;
        __syncthreads();
        for (int d = 1; d < 1024; d <<= 1) {
            int x = (t >= d) ? tmp[t - d] : 0;
            __syncthreads();
            tmp[t] += x;
            __syncthreads();
        }
        int excl = tmp[t] - v + carry;
        if (i < NB) { offsets[i] = excl; cursor[i] = excl; }
        __syncthreads();
        if (t == 1023) carry += tmp[1023];
        __syncthreads();
    }
    if (t == 0) offsets[NB] = carry;
}

__global__ void k_scatter_b(const int* __restrict__ src, const int* __restrict__ dst,
                            const float* __restrict__ ew, int* __restrict__ cursor_b,
                            int2* __restrict__ rec, int E, int NB) {
    extern __shared__ int sh[];
    int* h    = sh;
    int* base = sh + NB;
    for (int i = threadIdx.x; i < NB; i += blockDim.x) h[i] = 0;
    __syncthreads();
    int chunk = (E + gridDim.x - 1) / gridDim.x;
    int e0 = blockIdx.x * chunk;
    int e1 = min(E, e0 + chunk);
    for (int e = e0 + threadIdx.x; e < e1; e += blockDim.x)
        atomicAdd(&h[dst[e] >> BSHIFT], 1);
    __syncthreads();
    for (int i = threadIdx.x; i < NB; i += blockDim.x) {
        int c = h[i];
        base[i] = c ? atomicAdd(&cursor_b[i], c) : 0;
        h[i] = 0;
    }
    __syncthreads();
    for (int e = e0 + threadIdx.x; e < e1; e += blockDim.x) {
        int d = dst[e];
        int b = d >> BSHIFT;
        int p = base[b] + atomicAdd(&h[b], 1);
        rec[p] = make_int2(src[e] | ((d & (BROWS - 1)) << 25), __float_as_int(ew[e]));
    }
}

__global__ void k_sort_bucket(const int* __restrict__ offsets_b, int2* __restrict__ rec,
                              int* __restrict__ node_off, int* __restrict__ node_cnt,
                              int N) {
    __shared__ int2 L[CAP_R5];
    __shared__ int hist[BROWS];
    __shared__ int incl[BROWS];
    int b = blockIdx.x, t = threadIdx.x;
    int base  = offsets_b[b];
    int end   = offsets_b[b + 1];
    int count = end - base;
    int nbase = b << BSHIFT;

    if (count > CAP_R5) {
        for (int i = t; i < BROWS; i += blockDim.x) {
            int n = nbase + i;
            if (n < N) { node_off[n] = -(base + 1); node_cnt[n] = count; }
        }
        return;
    }
    for (int i = t; i < BROWS; i += blockDim.x) hist[i] = 0;
    __syncthreads();
    for (int i = t; i < count; i += blockDim.x) {
        int2 r = rec[base + i];
        L[i] = r;
        atomicAdd(&hist[(r.x >> 25) & (BROWS - 1)], 1);
    }
    __syncthreads();
    if (t < BROWS) incl[t] = hist[t];
    __syncthreads();
    for (int d = 1; d < BROWS; d <<= 1) {
        int v = (t < BROWS && t >= d) ? incl[t - d] : 0;
        __syncthreads();
        if (t < BROWS) incl[t] += v;
        __syncthreads();
    }
    if (t < BROWS) {
        int ex = incl[t] - hist[t];
        int n  = nbase + t;
        if (n < N) { node_off[n] = base + ex; node_cnt[n] = hist[t]; }
        hist[t] = ex;
    }
    __syncthreads();
    for (int i = t; i < count; i += blockDim.x) {
        int2 r = L[i];
        int pos = atomicAdd(&hist[(r.x >> 25) & (BROWS - 1)], 1);
        rec[base + pos] = r;
    }
}

__global__ void k_gather(const float* __restrict__ src_x,
                         const int* __restrict__ node_off, const int* __restrict__ node_cnt,
                         const int2* __restrict__ rec,
                         float* __restrict__ out, int N) {
    int wid  = (blockIdx.x * blockDim.x + threadIdx.x) >> 6;
    int lane = threadIdx.x & 63;
    if (wid >= N) return;
    int off = node_off[wid];
    int deg = node_cnt[wid];
    float acc = 0.f;
    if (off >= 0) {
        for (int bseg = 0; bseg < deg; bseg += 64) {
            int m = deg - bseg;
            if (m > 64) m = 64;
            int2 r = (lane < m) ? rec[off + bseg + lane] : make_int2(0, 0);
            int   rs = r.x;
            float rw = __int_as_float(r.y);
            int i = 0;
            for (; i + 4 <= m; i += 4) {
                int s0 = __shfl(rs, i + 0) & SRC_MASK, s1 = __shfl(rs, i + 1) & SRC_MASK;
                int s2 = __shfl(rs, i + 2) & SRC_MASK, s3 = __shfl(rs, i + 3) & SRC_MASK;
                float w0 = __shfl(rw, i + 0), w1 = __shfl(rw, i + 1);
                float w2 = __shfl(rw, i + 2), w3 = __shfl(rw, i + 3);
                float v0 = src_x[(size_t)s0 * D_FEAT + lane];
                float v1 = src_x[(size_t)s1 * D_FEAT + lane];
                float v2 = src_x[(size_t)s2 * D_FEAT + lane];
                float v3 = src_x[(size_t)s3 * D_FEAT + lane];
                acc = fmaf(w0, v0, acc);
                acc = fmaf(w1, v1, acc);
                acc = fmaf(w2, v2, acc);
                acc = fmaf(w3, v3, acc);
            }
            for (; i < m; ++i) {
                int   s = __shfl(rs, i) & SRC_MASK;
                float w = __shfl(rw, i);
                acc = fmaf(w, src_x[(size_t)s * D_FEAT + lane], acc);
            }
        }
    } else {
        int base  = -off - 1;
        int local = wid & (BROWS - 1);
        for (int i = 0; i < deg; ++i) {
            int2 r = rec[base + i];
            if (((r.x >> 25) & (BROWS - 1)) == local)
                acc = fmaf(__int_as_float(r.y),
                           src_x[(size_t)(r.x & SRC_MASK) * D_FEAT + lane], acc);
        }
    }
    out[(size_t)wid * D_FEAT + lane] = acc;
}

// ================= host =================

extern "C" void kernel_launch(void* const* d_in, const int* in_sizes, int n_in,
                              void* d_out, int out_size, void* d_ws, size_t ws_size,
                              hipStream_t stream) {
    const float* src_x      = (const float*)d_in[0];
    const int*   edge_index = (const int*)d_in[2];
    const float* ew         = (const float*)d_in[3];
    float*       out        = (float*)d_out;

    const int E = in_sizes[3];            // edge_weight [E,1]
    const int N = in_sizes[1] / D_FEAT;   // dst_x [N, 64]
    const int* src = edge_index;          // row 0
    const int* dst = edge_index + E;      // row 1

    const int NB = (N + BROWS - 1) >> BSHIFT;
    auto align256 = [](size_t x) { return (x + 255) & ~(size_t)255; };
    const int block = 256;

    // ---- full path: deterministic scatter + fused sort+gather ----
    {
        size_t off = 0;
        size_t C_off      = off; off += align256((size_t)NB * B_SC * 4);
        size_t btot_off   = off; off += align256((size_t)NB * 4);
        size_t rec_off    = off; off += align256(((size_t)NB * CAPF + 64) * 8);
        size_t ovf_off    = off; off += align256((size_t)OVF_CAP * 4);
        size_t ovfc_off   = off; off += 256;
        size_t sxb_off    = off; off += align256((size_t)N * D_FEAT * 2);
        size_t need_full  = off;

        if (ws_size >= need_full && N <= (1 << 25) && (size_t)NB * 4 <= 60 * 1024) {
            char* w = (char*)d_ws;
            int*            C       = (int*)(w + C_off);
            int*            btot    = (int*)(w + btot_off);
            int2*           rec     = (int2*)(w + rec_off);
            int*            ovf     = (int*)(w + ovf_off);
            int*            ovf_cnt = (int*)(w + ovfc_off);
            unsigned short* sxb     = (unsigned short*)(w + sxb_off);

            const int NE4 = N * (D_FEAT / 4);
            k_conv_hist<<<B_SC, block, (size_t)NB * 4, stream>>>(src_x, sxb, dst, C, NE4, E, NB);
            k_scan_det<<<NB, B_SC, 0, stream>>>(C, btot, ovf_cnt, NB);
            k_scatter_det<<<B_SC, block, (size_t)NB * 4, stream>>>(src, dst, ew, C, rec,
                                                                   ovf, ovf_cnt, E, NB);
            k_sort_gather<<<NB, 512, 0, stream>>>(btot, rec, sxb, src, dst, ew,
                                                  ovf, ovf_cnt, out, N);
            return;
        }
    }

    // ---- mid tier: round-5 pipeline ----
    {
        size_t off = 0;
        size_t counts_off  = off; off += align256((size_t)NB * 4);
        size_t offsets_off = off; off += align256((size_t)(NB + 1) * 4);
        size_t cursor_off  = off; off += align256((size_t)NB * 4);
        size_t noff_off    = off; off += align256((size_t)N * 4);
        size_t ncnt_off    = off; off += align256((size_t)N * 4);
        size_t rec_off     = off; off += align256((size_t)E * 8);
        size_t need_r5 = off;

        if (ws_size >= need_r5 && N <= (1 << 25) && (size_t)NB * 8 <= 60 * 1024) {
            char* w = (char*)d_ws;
            int*  counts_b  = (int*)(w + counts_off);
            int*  offsets_b = (int*)(w + offsets_off);
            int*  cursor_b  = (int*)(w + cursor_off);
            int*  node_off  = (int*)(w + noff_off);
            int*  node_cnt  = (int*)(w + ncnt_off);
            int2* rec       = (int2*)(w + rec_off);

            hipMemsetAsync(counts_b, 0, (size_t)NB * 4, stream);
            const int B = 256;
            k_hist_b<<<B, block, (size_t)NB * 4, stream>>>(dst, counts_b, E, NB);
            k_scan_b<<<1, 1024, 0, stream>>>(counts_b, offsets_b, cursor_b, NB);
            k_scatter_b<<<B, block, (size_t)NB * 8, stream>>>(src, dst, ew, cursor_b, rec, E, NB);
            k_sort_bucket<<<NB, block, 0, stream>>>(offsets_b, rec, node_off, node_cnt, N);
            k_gather<<<(N + 3) / 4, 256, 0, stream>>>(src_x, node_off, node_cnt, rec, out, N);
            return;
        }
    }

    // ---- fallback: round-1 atomic path ----
    hipMemsetAsync(d_out, 0, (size_t)out_size * sizeof(float), stream);
    const long long total = (long long)E * 16;
    const int grid = (int)((total + block - 1) / block);
    lgconv_scatter_atomic<<<grid, block, 0, stream>>>(src_x, src, dst, ew, out, E);
}

// Round 19
// 66.856 us; speedup vs baseline: 1.1467x; 1.1467x over previous
//
#include <hip/hip_runtime.h>

#define D_FEAT   64
#define BSHIFT   7                // 128 nodes per coarse bucket
#define BROWS    (1 << BSHIFT)
#define SRC_MASK 0x1FFFFFF        // 25 bits for src index
#define CAPF     2816             // bucket region stride in rec[]
#define CAPF_RAW 1920             // raw-record cap (mean 1600, sd 40 -> 8 sigma)
#define OVF_CAP  16384
#define CAP_R5   2560             // mid-tier sort capacity
#define B_SC     512              // chunking blocks for count/write phases

__device__ __forceinline__ unsigned short f2bf(float f) {
    unsigned u = __float_as_uint(f);
    u += 0x7FFF + ((u >> 16) & 1);   // round-to-nearest-even
    return (unsigned short)(u >> 16);
}
__device__ __forceinline__ float lo16f(unsigned u) { return __uint_as_float(u << 16); }
__device__ __forceinline__ float hi16f(unsigned u) { return __uint_as_float(u & 0xFFFF0000u); }
__device__ __forceinline__ float bf2f(unsigned short h) { return __uint_as_float(((unsigned)h) << 16); }

// ---------------- fallback (round-1) atomic kernel ----------------
__global__ void lgconv_scatter_atomic(const float* __restrict__ src_x,
                                      const int* __restrict__ src_idx,
                                      const int* __restrict__ dst_idx,
                                      const float* __restrict__ ew,
                                      float* __restrict__ out,
                                      int n_edges) {
    int tid = blockIdx.x * blockDim.x + threadIdx.x;
    int edge = tid >> 4;
    int l    = tid & 15;
    if (edge >= n_edges) return;
    int s = src_idx[edge];
    int d = dst_idx[edge];
    float w = ew[edge];
    const float4 v = *reinterpret_cast<const float4*>(src_x + (size_t)s * D_FEAT + l * 4);
    float* o = out + (size_t)d * D_FEAT + l * 4;
    atomicAdd(o + 0, w * v.x);
    atomicAdd(o + 1, w * v.y);
    atomicAdd(o + 2, w * v.z);
    atomicAdd(o + 3, w * v.w);
}

// ======== FULL PATH: deterministic scatter + fused in-LDS sort+gather ========

// Fused: src_x -> bf16 rows + per-(block,bucket) count matrix C[bucket*B_SC+blk].
// Edge hist pass vectorized: int4 dst loads (4 edges/thread).
__global__ void k_conv_hist(const float* __restrict__ src_x, unsigned short* __restrict__ sxb,
                            const int* __restrict__ dst, int* __restrict__ C,
                            int NE4, int E, int NB) {
    extern __shared__ int h[];
    int t = threadIdx.x, blk = blockIdx.x;
    int gsz = gridDim.x * blockDim.x;
    for (int i = blk * blockDim.x + t; i < NE4; i += gsz) {
        float4 v = reinterpret_cast<const float4*>(src_x)[i];
        ushort4 o;
        o.x = f2bf(v.x); o.y = f2bf(v.y); o.z = f2bf(v.z); o.w = f2bf(v.w);
        reinterpret_cast<ushort4*>(sxb)[i] = o;
    }
    for (int i = t; i < NB; i += blockDim.x) h[i] = 0;
    __syncthreads();
    int chunk = (((E + gridDim.x - 1) / gridDim.x) + 3) & ~3;   // multiple of 4
    int e0 = blk * chunk, e1 = min(E, e0 + chunk);
    if (e0 < e1) {
        int nv = (e1 - e0) >> 2;
        for (int g = t; g < nv; g += blockDim.x) {
            int4 d4 = *reinterpret_cast<const int4*>(dst + e0 + g * 4);
            atomicAdd(&h[d4.x >> BSHIFT], 1);
            atomicAdd(&h[d4.y >> BSHIFT], 1);
            atomicAdd(&h[d4.z >> BSHIFT], 1);
            atomicAdd(&h[d4.w >> BSHIFT], 1);
        }
        for (int e = e0 + nv * 4 + t; e < e1; e += blockDim.x)
            atomicAdd(&h[dst[e] >> BSHIFT], 1);
    }
    __syncthreads();
    for (int i = t; i < NB; i += blockDim.x)
        C[i * B_SC + blk] = h[i];
}

// Per-bucket exclusive scan over the B_SC block counts, in place.
__global__ void k_scan_det(int* __restrict__ C, int* __restrict__ btot,
                           int* __restrict__ ovf_cnt, int NB) {
    __shared__ int tmp[B_SC];
    int b = blockIdx.x, t = threadIdx.x;
    int v = C[b * B_SC + t];
    tmp[t] = v;
    __syncthreads();
    for (int d = 1; d < B_SC; d <<= 1) {
        int x = (t >= d) ? tmp[t - d] : 0;
        __syncthreads();
        tmp[t] += x;
        __syncthreads();
    }
    C[b * B_SC + t] = b * CAPF + tmp[t] - v;
    if (t == B_SC - 1) btot[b] = tmp[t];
    if (b == 0 && t == 0) *ovf_cnt = 0;
}

// Write records at exact precomputed positions. ZERO global atomics.
// Vectorized: 4 edges/thread via int4/float4 loads (MLP~3 on the input loads).
__global__ void k_scatter_det(const int* __restrict__ src, const int* __restrict__ dst,
                              const float* __restrict__ ew, const int* __restrict__ OFF,
                              int2* __restrict__ rec, int* __restrict__ ovf,
                              int* __restrict__ ovf_cnt, int E, int NB) {
    extern __shared__ int h[];
    int t = threadIdx.x, blk = blockIdx.x;
    for (int i = t; i < NB; i += blockDim.x) h[i] = OFF[i * B_SC + blk];
    __syncthreads();
    int chunk = (((E + gridDim.x - 1) / gridDim.x) + 3) & ~3;   // multiple of 4
    int e0 = blk * chunk, e1 = min(E, e0 + chunk);
    if (e0 >= e1) return;

    int nv = (e1 - e0) >> 2;
    for (int g = t; g < nv; g += blockDim.x) {
        int    base4 = e0 + g * 4;
        int4   d4 = *reinterpret_cast<const int4*>(dst + base4);
        int4   s4 = *reinterpret_cast<const int4*>(src + base4);
        float4 w4 = *reinterpret_cast<const float4*>(ew + base4);
        #pragma unroll
        for (int q = 0; q < 4; ++q) {
            int   d = (q == 0) ? d4.x : (q == 1) ? d4.y : (q == 2) ? d4.z : d4.w;
            int   s = (q == 0) ? s4.x : (q == 1) ? s4.y : (q == 2) ? s4.z : s4.w;
            float w = (q == 0) ? w4.x : (q == 1) ? w4.y : (q == 2) ? w4.z : w4.w;
            int b = d >> BSHIFT;
            int pos = atomicAdd(&h[b], 1);           // LDS only
            if (pos < b * CAPF + CAPF_RAW)
                rec[pos] = make_int2(s | ((d & (BROWS - 1)) << 25),
                                     ((int)f2bf(w)) << 16);
            else {
                int o = atomicAdd(ovf_cnt, 1);       // statistically never
                if (o < OVF_CAP) ovf[o] = base4 + q;
            }
        }
    }
    for (int e = e0 + nv * 4 + t; e < e1; e += blockDim.x) {
        int d = dst[e];
        int b = d >> BSHIFT;
        int pos = atomicAdd(&h[b], 1);
        if (pos < b * CAPF + CAPF_RAW)
            rec[pos] = make_int2(src[e] | ((d & (BROWS - 1)) << 25),
                                 ((int)f2bf(ew[e])) << 16);
        else {
            int o = atomicAdd(ovf_cnt, 1);
            if (o < OVF_CAP) ovf[o] = e;
        }
    }
}

// One block (8 waves) per bucket. Records stream ONCE from global into an
// arrival-order LDS buffer L (hist computed on the fly), then LDS->LDS permute
// into sorted S. Gather: ONE NODE PER 8-LANE GROUP, branch-free inner loop,
// 8 independent row loads in flight (MLP=8), no cross-group reduce.
__global__ __launch_bounds__(512)
void k_sort_gather(const int* __restrict__ btot, const int2* __restrict__ rec,
                   const unsigned short* __restrict__ sxb,
                   const int* __restrict__ src, const int* __restrict__ dst,
                   const float* __restrict__ ew,
                   const int* __restrict__ ovf, const int* __restrict__ ovf_cnt,
                   float* __restrict__ out, int N) {
    __shared__ int2 L[CAPF_RAW];      // 15 KB arrival-order records
    __shared__ int2 S[CAPF_RAW];      // 15 KB node-sorted records
    __shared__ int hist[BROWS];
    __shared__ int incl[BROWS];
    __shared__ int offl[BROWS];
    int b = blockIdx.x, t = threadIdx.x;
    int gbase = b * CAPF;
    int count = btot[b]; if (count > CAPF_RAW) count = CAPF_RAW;
    int nbase = b << BSHIFT;

    // ---- single global read: fill L + hist ----
    for (int i = t; i < BROWS; i += blockDim.x) hist[i] = 0;
    __syncthreads();
    for (int i = t; i < count; i += blockDim.x) {
        int2 r = rec[gbase + i];
        L[i] = r;
        atomicAdd(&hist[(r.x >> 25) & (BROWS - 1)], 1);
    }
    __syncthreads();
    if (t < BROWS) incl[t] = hist[t];
    __syncthreads();
    for (int d = 1; d < BROWS; d <<= 1) {
        int v = (t < BROWS && t >= d) ? incl[t - d] : 0;
        __syncthreads();
        if (t < BROWS) incl[t] += v;
        __syncthreads();
    }
    if (t < BROWS) {
        int ex = incl[t] - hist[t];
        offl[t] = ex;
        incl[t] = ex;                    // write cursor
    }
    __syncthreads();
    for (int i = t; i < count; i += blockDim.x) {
        int2 r = L[i];                   // LDS -> LDS permute
        int pos = atomicAdd(&incl[(r.x >> 25) & (BROWS - 1)], 1);
        S[pos] = r;
    }
    __syncthreads();

    // ---- gather: 8 nodes per wave, one per 8-lane group ----
    int wave = t >> 6, lane = t & 63;
    int grp = lane >> 3;      // node within the batch of 8
    int sub = lane & 7;       // dwordx4 slot within the 128 B bf16 row

    for (int kb = wave * 16; kb < wave * 16 + 16; kb += 8) {
        int k    = kb + grp;            // this group's local node
        int off  = offl[k];
        int deg  = hist[k];             // group-uniform per lane
        float a0 = 0.f, a1 = 0.f, a2 = 0.f, a3 = 0.f,
              a4 = 0.f, a5 = 0.f, a6 = 0.f, a7 = 0.f;

        for (int c = 0; __any(c < deg); c += 8) {
            int rs = 0; float rw = 0.f;
            if (c + sub < deg) {                     // in-bounds: off+c+sub < count
                int2 r = S[off + c + sub];
                rs = r.x;
                rw = hi16f((unsigned)r.y);
            }
            #pragma unroll
            for (int i = 0; i < 8; ++i) {
                int jl = (grp << 3) + i;             // intra-group broadcast
                int   s = __shfl(rs, jl) & SRC_MASK; // pad slots -> row 0 (L1-hot)
                float w = __shfl(rw, jl);            // pad slots -> w = 0
                const uint4 u = *reinterpret_cast<const uint4*>(
                    sxb + (size_t)s * D_FEAT + sub * 8);
                a0 = fmaf(w, lo16f(u.x), a0); a1 = fmaf(w, hi16f(u.x), a1);
                a2 = fmaf(w, lo16f(u.y), a2); a3 = fmaf(w, hi16f(u.y), a3);
                a4 = fmaf(w, lo16f(u.z), a4); a5 = fmaf(w, hi16f(u.z), a5);
                a6 = fmaf(w, lo16f(u.w), a6); a7 = fmaf(w, hi16f(u.w), a7);
            }
        }
        int node = nbase + k;
        if (node < N) {
            float* o = out + (size_t)node * D_FEAT + sub * 8;
            *reinterpret_cast<float4*>(o)     = make_float4(a0, a1, a2, a3);
            *reinterpret_cast<float4*>(o + 4) = make_float4(a4, a5, a6, a7);
        }
    }

    // ---- overflow replay for this bucket (normally n == 0) ----
    __syncthreads();
    int n = *ovf_cnt; if (n > OVF_CAP) n = OVF_CAP;
    for (int idx = t; idx < n; idx += blockDim.x) {
        int e = ovf[idx];
        int d = dst[e];
        if ((d >> BSHIFT) != b) continue;
        float w = ew[e];
        int s = src[e];
        for (int q = 0; q < D_FEAT; ++q)
            atomicAdd(out + (size_t)d * D_FEAT + q,
                      w * bf2f(sxb[(size_t)s * D_FEAT + q]));
    }
}

// ================= MID TIER (proven round-5 pipeline, f32) =================

__global__ void k_hist_b(const int* __restrict__ dst, int* __restrict__ counts_b,
                         int E, int NB) {
    extern __shared__ int h[];
    for (int i = threadIdx.x; i < NB; i += blockDim.x) h[i] = 0;
    __syncthreads();
    int chunk = (E + gridDim.x - 1) / gridDim.x;
    int e0 = blockIdx.x * chunk;
    int e1 = min(E, e0 + chunk);
    for (int e = e0 + threadIdx.x; e < e1; e += blockDim.x)
        atomicAdd(&h[dst[e] >> BSHIFT], 1);
    __syncthreads();
    for (int i = threadIdx.x; i < NB; i += blockDim.x)
        if (h[i]) atomicAdd(&counts_b[i], h[i]);
}

__global__ void k_scan_b(const int* __restrict__ counts, int* __restrict__ offsets,
                         int* __restrict__ cursor, int NB) {
    __shared__ int tmp[1024];
    __shared__ int carry;
    int t = threadIdx.x;
    if (t == 0) carry = 0;
    __syncthreads();
    for (int base = 0; base < NB; base += 1024) {
        int i = base + t;
        int v = (i < NB) ? counts[i] : 0;
        tmp[t] = v;
        __syncthreads();
        for (int d = 1; d < 1024; d <<= 1) {
            int x = (t >= d) ? tmp[t - d] : 0;
            __syncthreads();
            tmp[t] += x;
            __syncthreads();
        }
        int excl = tmp[t] - v + carry;
        if (i < NB) { offsets[i] = excl; cursor[i] = excl; }
        __syncthreads();
        if (t == 1023) carry += tmp[1023];
        __syncthreads();
    }
    if (t == 0) offsets[NB] = carry;
}

__global__ void k_scatter_b(const int* __restrict__ src, const int* __restrict__ dst,
                            const float* __restrict__ ew, int* __restrict__ cursor_b,
                            int2* __restrict__ rec, int E, int NB) {
    extern __shared__ int sh[];
    int* h    = sh;
    int* base = sh + NB;
    for (int i = threadIdx.x; i < NB; i += blockDim.x) h[i] = 0;
    __syncthreads();
    int chunk = (E + gridDim.x - 1) / gridDim.x;
    int e0 = blockIdx.x * chunk;
    int e1 = min(E, e0 + chunk);
    for (int e = e0 + threadIdx.x; e < e1; e += blockDim.x)
        atomicAdd(&h[dst[e] >> BSHIFT], 1);
    __syncthreads();
    for (int i = threadIdx.x; i < NB; i += blockDim.x) {
        int c = h[i];
        base[i] = c ? atomicAdd(&cursor_b[i], c) : 0;
        h[i] = 0;
    }
    __syncthreads();
    for (int e = e0 + threadIdx.x; e < e1; e += blockDim.x) {
        int d = dst[e];
        int b = d >> BSHIFT;
        int p = base[b] + atomicAdd(&h[b], 1);
        rec[p] = make_int2(src[e] | ((d & (BROWS - 1)) << 25), __float_as_int(ew[e]));
    }
}

__global__ void k_sort_bucket(const int* __restrict__ offsets_b, int2* __restrict__ rec,
                              int* __restrict__ node_off, int* __restrict__ node_cnt,
                              int N) {
    __shared__ int2 L[CAP_R5];
    __shared__ int hist[BROWS];
    __shared__ int incl[BROWS];
    int b = blockIdx.x, t = threadIdx.x;
    int base  = offsets_b[b];
    int end   = offsets_b[b + 1];
    int count = end - base;
    int nbase = b << BSHIFT;

    if (count > CAP_R5) {
        for (int i = t; i < BROWS; i += blockDim.x) {
            int n = nbase + i;
            if (n < N) { node_off[n] = -(base + 1); node_cnt[n] = count; }
        }
        return;
    }
    for (int i = t; i < BROWS; i += blockDim.x) hist[i] = 0;
    __syncthreads();
    for (int i = t; i < count; i += blockDim.x) {
        int2 r = rec[base + i];
        L[i] = r;
        atomicAdd(&hist[(r.x >> 25) & (BROWS - 1)], 1);
    }
    __syncthreads();
    if (t < BROWS) incl[t] = hist[t];
    __syncthreads();
    for (int d = 1; d < BROWS; d <<= 1) {
        int v = (t < BROWS && t >= d) ? incl[t - d] : 0;
        __syncthreads();
        if (t < BROWS) incl[t] += v;
        __syncthreads();
    }
    if (t < BROWS) {
        int ex = incl[t] - hist[t];
        int n  = nbase + t;
        if (n < N) { node_off[n] = base + ex; node_cnt[n] = hist[t]; }
        hist[t] = ex;
    }
    __syncthreads();
    for (int i = t; i < count; i += blockDim.x) {
        int2 r = L[i];
        int pos = atomicAdd(&hist[(r.x >> 25) & (BROWS - 1)], 1);
        rec[base + pos] = r;
    }
}

__global__ void k_gather(const float* __restrict__ src_x,
                         const int* __restrict__ node_off, const int* __restrict__ node_cnt,
                         const int2* __restrict__ rec,
                         float* __restrict__ out, int N) {
    int wid  = (blockIdx.x * blockDim.x + threadIdx.x) >> 6;
    int lane = threadIdx.x & 63;
    if (wid >= N) return;
    int off = node_off[wid];
    int deg = node_cnt[wid];
    float acc = 0.f;
    if (off >= 0) {
        for (int bseg = 0; bseg < deg; bseg += 64) {
            int m = deg - bseg;
            if (m > 64) m = 64;
            int2 r = (lane < m) ? rec[off + bseg + lane] : make_int2(0, 0);
            int   rs = r.x;
            float rw = __int_as_float(r.y);
            int i = 0;
            for (; i + 4 <= m; i += 4) {
                int s0 = __shfl(rs, i + 0) & SRC_MASK, s1 = __shfl(rs, i + 1) & SRC_MASK;
                int s2 = __shfl(rs, i + 2) & SRC_MASK, s3 = __shfl(rs, i + 3) & SRC_MASK;
                float w0 = __shfl(rw, i + 0), w1 = __shfl(rw, i + 1);
                float w2 = __shfl(rw, i + 2), w3 = __shfl(rw, i + 3);
                float v0 = src_x[(size_t)s0 * D_FEAT + lane];
                float v1 = src_x[(size_t)s1 * D_FEAT + lane];
                float v2 = src_x[(size_t)s2 * D_FEAT + lane];
                float v3 = src_x[(size_t)s3 * D_FEAT + lane];
                acc = fmaf(w0, v0, acc);
                acc = fmaf(w1, v1, acc);
                acc = fmaf(w2, v2, acc);
                acc = fmaf(w3, v3, acc);
            }
            for (; i < m; ++i) {
                int   s = __shfl(rs, i) & SRC_MASK;
                float w = __shfl(rw, i);
                acc = fmaf(w, src_x[(size_t)s * D_FEAT + lane], acc);
            }
        }
    } else {
        int base  = -off - 1;
        int local = wid & (BROWS - 1);
        for (int i = 0; i < deg; ++i) {
            int2 r = rec[base + i];
            if (((r.x >> 25) & (BROWS - 1)) == local)
                acc = fmaf(__int_as_float(r.y),
                           src_x[(size_t)(r.x & SRC_MASK) * D_FEAT + lane], acc);
        }
    }
    out[(size_t)wid * D_FEAT + lane] = acc;
}

// ================= host =================

extern "C" void kernel_launch(void* const* d_in, const int* in_sizes, int n_in,
                              void* d_out, int out_size, void* d_ws, size_t ws_size,
                              hipStream_t stream) {
    const float* src_x      = (const float*)d_in[0];
    const int*   edge_index = (const int*)d_in[2];
    const float* ew         = (const float*)d_in[3];
    float*       out        = (float*)d_out;

    const int E = in_sizes[3];            // edge_weight [E,1]
    const int N = in_sizes[1] / D_FEAT;   // dst_x [N, 64]
    const int* src = edge_index;          // row 0
    const int* dst = edge_index + E;      // row 1

    const int NB = (N + BROWS - 1) >> BSHIFT;
    auto align256 = [](size_t x) { return (x + 255) & ~(size_t)255; };
    const int block = 256;

    // ---- full path: deterministic scatter + fused sort+gather ----
    {
        size_t off = 0;
        size_t C_off      = off; off += align256((size_t)NB * B_SC * 4);
        size_t btot_off   = off; off += align256((size_t)NB * 4);
        size_t rec_off    = off; off += align256(((size_t)NB * CAPF + 64) * 8);
        size_t ovf_off    = off; off += align256((size_t)OVF_CAP * 4);
        size_t ovfc_off   = off; off += 256;
        size_t sxb_off    = off; off += align256((size_t)N * D_FEAT * 2);
        size_t need_full  = off;

        if (ws_size >= need_full && N <= (1 << 25) && (size_t)NB * 4 <= 60 * 1024) {
            char* w = (char*)d_ws;
            int*            C       = (int*)(w + C_off);
            int*            btot    = (int*)(w + btot_off);
            int2*           rec     = (int2*)(w + rec_off);
            int*            ovf     = (int*)(w + ovf_off);
            int*            ovf_cnt = (int*)(w + ovfc_off);
            unsigned short* sxb     = (unsigned short*)(w + sxb_off);

            const int NE4 = N * (D_FEAT / 4);
            k_conv_hist<<<B_SC, block, (size_t)NB * 4, stream>>>(src_x, sxb, dst, C, NE4, E, NB);
            k_scan_det<<<NB, B_SC, 0, stream>>>(C, btot, ovf_cnt, NB);
            k_scatter_det<<<B_SC, block, (size_t)NB * 4, stream>>>(src, dst, ew, C, rec,
                                                                   ovf, ovf_cnt, E, NB);
            k_sort_gather<<<NB, 512, 0, stream>>>(btot, rec, sxb, src, dst, ew,
                                                  ovf, ovf_cnt, out, N);
            return;
        }
    }

    // ---- mid tier: round-5 pipeline ----
    {
        size_t off = 0;
        size_t counts_off  = off; off += align256((size_t)NB * 4);
        size_t offsets_off = off; off += align256((size_t)(NB + 1) * 4);
        size_t cursor_off  = off; off += align256((size_t)NB * 4);
        size_t noff_off    = off; off += align256((size_t)N * 4);
        size_t ncnt_off    = off; off += align256((size_t)N * 4);
        size_t rec_off     = off; off += align256((size_t)E * 8);
        size_t need_r5 = off;

        if (ws_size >= need_r5 && N <= (1 << 25) && (size_t)NB * 8 <= 60 * 1024) {
            char* w = (char*)d_ws;
            int*  counts_b  = (int*)(w + counts_off);
            int*  offsets_b = (int*)(w + offsets_off);
            int*  cursor_b  = (int*)(w + cursor_off);
            int*  node_off  = (int*)(w + noff_off);
            int*  node_cnt  = (int*)(w + ncnt_off);
            int2* rec       = (int2*)(w + rec_off);

            hipMemsetAsync(counts_b, 0, (size_t)NB * 4, stream);
            const int B = 256;
            k_hist_b<<<B, block, (size_t)NB * 4, stream>>>(dst, counts_b, E, NB);
            k_scan_b<<<1, 1024, 0, stream>>>(counts_b, offsets_b, cursor_b, NB);
            k_scatter_b<<<B, block, (size_t)NB * 8, stream>>>(src, dst, ew, cursor_b, rec, E, NB);
            k_sort_bucket<<<NB, block, 0, stream>>>(offsets_b, rec, node_off, node_cnt, N);
            k_gather<<<(N + 3) / 4, 256, 0, stream>>>(src_x, node_off, node_cnt, rec, out, N);
            return;
        }
    }

    // ---- fallback: round-1 atomic path ----
    hipMemsetAsync(d_out, 0, (size_t)out_size * sizeof(float), stream);
    const long long total = (long long)E * 16;
    const int grid = (int)((total + block - 1) / block);
    lgconv_scatter_atomic<<<grid, block, 0, stream>>>(src_x, src, dst, ew, out, E);
}